// Round 18
// baseline (98.743 us; speedup 1.0000x reference)
//
#include <hip/hip_runtime.h>
#include <hip/hip_bf16.h>

// Problem shape (fixed by setup_inputs): B=8, Q=2048 -> N=16384 rows,
// D=1024, Dp=256, K=2048 prototypes.
#define N_ROWS 16384
#define DIM    1024
#define DP     256
#define NPROTO 2048

typedef float f32x4 __attribute__((ext_vector_type(4)));
typedef short s16x8 __attribute__((ext_vector_type(8)));
typedef short s16x4 __attribute__((ext_vector_type(4)));

__device__ __forceinline__ unsigned short f2bf(float f) {
  __hip_bfloat16 h = __float2bfloat16(f);   // RNE
  return __builtin_bit_cast(unsigned short, h);
}

// LDS-only barrier (no vmcnt drain; global prefetches stay in flight).
__device__ __forceinline__ void lds_barrier() {
  asm volatile("s_waitcnt lgkmcnt(0)" ::: "memory");
  __builtin_amdgcn_s_barrier();
}

// ---- prep: build FRAGMENT-ORDER operands ----
// projT_sw[cg][kb][lane][8]: cg in [0,16), kb in [0,32);
//   lane's 8 bf16 = proj[kb*32+(lane>>4)*8+j][cg*16+(lane&15)].
// Pb_sw[pgrp][kb][lane][8]: pgrp in [0,128), kb in [0,8);
//   lane's 8 bf16 = proto[pgrp*16+(lane&15)][kb*32+(lane>>4)*8+j].
// A wave's MFMA B-fragment load is then base + lane*16B: one coalesced 1KB read.
__global__ void k_prep(const float* __restrict__ proj,
                       const float* __restrict__ P,
                       unsigned short* __restrict__ projT_sw,
                       unsigned short* __restrict__ Pb_sw,
                       float* __restrict__ pp) {
  int b = blockIdx.x;
  int t = threadIdx.x;
  if (b < 128) {                      // projT_sw: 32768 16B chunks
    int q    = b * 256 + t;
    int lane = q & 63, kb = (q >> 6) & 31, cg = q >> 11;
    int c  = cg * 16 + (lane & 15);
    int k0 = kb * 32 + (lane >> 4) * 8;
    s16x8 v;
#pragma unroll
    for (int j = 0; j < 8; ++j)
      v[j] = (short)f2bf(proj[(size_t)(k0 + j) * DP + c]);
    *(s16x8*)(projT_sw + (size_t)q * 8) = v;
  } else if (b < 384) {               // Pb_sw: 65536 16B chunks
    int q    = (b - 128) * 256 + t;
    int lane = q & 63, kb = (q >> 6) & 7, pg = q >> 9;
    const float* src = P + (size_t)(pg * 16 + (lane & 15)) * DP +
                       kb * 32 + (lane >> 4) * 8;
    s16x8 v;
#pragma unroll
    for (int j = 0; j < 8; ++j) v[j] = (short)f2bf(src[j]);
    *(s16x8*)(Pb_sw + (size_t)q * 8) = v;
  } else {                            // pp: one block per proto
    int k = b - 384;
    float v = P[(size_t)k * DP + t];
    float s = v * v;
#pragma unroll
    for (int o = 1; o < 64; o <<= 1) s += __shfl_xor(s, o, 64);
    __shared__ float ws4[4];
    if ((t & 63) == 0) ws4[t >> 6] = s;
    __syncthreads();
    if (t == 0) pp[k] = ws4[0] + ws4[1] + ws4[2] + ws4[3];
  }
}

// ---- FUSED: 32 rows/block, 512 threads = 8 waves, grid 512 -> 2 blocks/CU ----
// (R11 champion, restored byte-for-byte. R12-R17 all regressed: any extra
//  named-register state beyond this structure spills to scratch at the
//  compiler's 64-VGPR allocation, costing ~+77MB HBM / +37us.)
// Phase 1 (16 steps, BK=64, lds_barrier only): X staged via LDS, 2-deep reg
//   prefetch; B reg-direct coalesced from projT_sw.
// Handoff: row-norms, normalized Z -> Zs (3 lds_barriers).
// Phase 2 (ZERO barriers): each wave owns ALL 32 rows x protos wv*256..+256;
//   A re-read per-ks from Zs (2-way-conflict ds_read, free); B 2-deep named
//   prefetch (brA/brB); per-row 256B contiguous stores (full-line writes).
__global__ __launch_bounds__(512, 4)
void k_fused(const float* __restrict__ X, const float* __restrict__ mean,
             const unsigned short* __restrict__ projT_sw,
             const unsigned short* __restrict__ Pb_sw,
             const float* __restrict__ pp, float* __restrict__ out) {
  __shared__ __align__(16) unsigned short Zs[32][264];   // 16896 B
  __shared__ __align__(16) unsigned short As[2][32][72]; //  9216 B
  __shared__ __align__(16) float mean_s[DIM];            //  4096 B
  __shared__ float rowsq[8][32];                         //  1024 B
  __shared__ float invs[32];                             //   128 B

  const int tid  = threadIdx.x;
  const int lane = tid & 63;
  const int wv   = tid >> 6;        // wave id 0..7
  const int l15  = lane & 15;
  const int lhi  = lane >> 4;
  const int rb   = blockIdx.x * 32;

  // stage mean once
  if (tid < 256)
    *(f32x4*)&mean_s[tid * 4] = *(const f32x4*)(mean + tid * 4);
  __syncthreads();

  // phase-1 staging coords: thread stages row tid>>4, cols (tid&15)*4 (+t*64)
  const int arow = tid >> 4;             // [0,32)
  const int ach  = (tid & 15) * 4;
  const float* xbase = X + (size_t)(rb + arow) * DIM + ach;
  // phase-1 B base: wave wv covers col-groups 2wv, 2wv+1
  const unsigned short* pj_base =
      projT_sw + (size_t)(wv * 2) * 32 * 64 * 8 + (size_t)lane * 8;

  f32x4 acc[2][2];
#pragma unroll
  for (int mf = 0; mf < 2; ++mf)
#pragma unroll
    for (int cg = 0; cg < 2; ++cg) acc[mf][cg] = (f32x4)0.0f;

  f32x4 xA, xB;
  s16x8 bfA[4], bfB[4];   // [cgi*2+kk]

#define P1X(XR, T) { XR = *(const f32x4*)(xbase + (T) * 64); }
#define P1B(REGS, T)                                                         \
  {                                                                          \
    _Pragma("unroll")                                                        \
    for (int cgi = 0; cgi < 2; ++cgi)                                        \
      _Pragma("unroll")                                                      \
      for (int kk = 0; kk < 2; ++kk)                                         \
        REGS[cgi * 2 + kk] = *(const s16x8*)(pj_base +                       \
            (size_t)(cgi * 32 + (T) * 2 + kk) * 512);                        \
  }
#define P1W(CUR, XR, T)                                                      \
  {                                                                          \
    f32x4 m0 = *(const f32x4*)&mean_s[(T) * 64 + ach];                       \
    f32x4 c0 = XR - m0;                                                      \
    s16x4 v;                                                                 \
    v[0] = (short)f2bf(c0[0]); v[1] = (short)f2bf(c0[1]);                    \
    v[2] = (short)f2bf(c0[2]); v[3] = (short)f2bf(c0[3]);                    \
    *(s16x4*)(&As[CUR][arow][ach]) = v;                                      \
  }
#define P1C(CUR, BF)                                                         \
  {                                                                          \
    s16x8 a[2][2];                                                           \
    _Pragma("unroll")                                                        \
    for (int mf = 0; mf < 2; ++mf)                                           \
      _Pragma("unroll")                                                      \
      for (int kk = 0; kk < 2; ++kk)                                         \
        a[mf][kk] = *(const s16x8*)(&As[CUR][mf * 16 + l15][kk * 32 + lhi * 8]); \
    _Pragma("unroll")                                                        \
    for (int mf = 0; mf < 2; ++mf)                                           \
      _Pragma("unroll")                                                      \
      for (int cgi = 0; cgi < 2; ++cgi)                                      \
        _Pragma("unroll")                                                    \
        for (int kk = 0; kk < 2; ++kk)                                       \
          acc[mf][cgi] = __builtin_amdgcn_mfma_f32_16x16x32_bf16(            \
              a[mf][kk], BF[cgi * 2 + kk], acc[mf][cgi], 0, 0, 0);           \
  }

  P1X(xA, 0); P1B(bfA, 0);
  P1X(xB, 1); P1B(bfB, 1);
  for (int t = 0; t < 16; t += 2) {
    P1W(0, xA, t);
    if (t + 2 < 16) P1X(xA, t + 2);
    lds_barrier();
    P1C(0, bfA);
    if (t + 2 < 16) P1B(bfA, t + 2);
    P1W(1, xB, t + 1);
    if (t + 3 < 16) P1X(xB, t + 3);
    lds_barrier();
    P1C(1, bfB);
    if (t + 3 < 16) P1B(bfB, t + 3);
  }
#undef P1X
#undef P1B
#undef P1W
#undef P1C

  // issue phase-2 B loads (2-deep) now; they survive the handoff
  // lds_barriers. wave wv owns protos wv*256..+256.
  const unsigned short* pb_base =
      Pb_sw + (size_t)(wv * 16) * 8 * 64 * 8 + (size_t)lane * 8;
  s16x8 brA[4], brB[4];
#define P2B(REGS, T)                                                         \
  {                                                                          \
    const int g_ = (T) >> 3, k_ = (T) & 7;                                   \
    _Pragma("unroll")                                                        \
    for (int nf = 0; nf < 4; ++nf)                                           \
      REGS[nf] = *(const s16x8*)(pb_base +                                   \
          (size_t)((g_ * 4 + nf) * 8 + k_) * 512);                           \
  }
  P2B(brA, 0);
  P2B(brB, 1);

  // ---- handoff: row norms + normalized Z -> Zs ----
#pragma unroll
  for (int mf = 0; mf < 2; ++mf)
#pragma unroll
    for (int r = 0; r < 4; ++r) {
      float s = acc[mf][0][r] * acc[mf][0][r] + acc[mf][1][r] * acc[mf][1][r];
#pragma unroll
      for (int o = 1; o < 16; o <<= 1) s += __shfl_xor(s, o, 16);
      if (l15 == 0) rowsq[wv][mf * 16 + lhi * 4 + r] = s;
    }
  lds_barrier();
  if (tid < 32) {
    float n2 = 0.0f;
#pragma unroll
    for (int w = 0; w < 8; ++w) n2 += rowsq[w][tid];
    invs[tid] = 1.0f / fmaxf(sqrtf(n2), 1e-12f);  // F.normalize eps
  }
  lds_barrier();
#pragma unroll
  for (int mf = 0; mf < 2; ++mf)
#pragma unroll
    for (int r = 0; r < 4; ++r) {
      int row   = mf * 16 + lhi * 4 + r;
      float inv = invs[row];
#pragma unroll
      for (int cgi = 0; cgi < 2; ++cgi)
        Zs[row][wv * 32 + cgi * 16 + l15] = f2bf(acc[mf][cgi][r] * inv);
    }
  lds_barrier();

  // ================= phase 2 (no barriers) =================
  const float* ppb = pp + wv * 256;
  float* outb = out + (size_t)rb * NPROTO + wv * 256;

#define P2KS(KS, G, REGS)                                                    \
  {                                                                          \
    s16x8 a0 = *(const s16x8*)(&Zs[l15][(KS) * 32 + lhi * 8]);               \
    s16x8 a1 = *(const s16x8*)(&Zs[16 + l15][(KS) * 32 + lhi * 8]);          \
    _Pragma("unroll")                                                        \
    for (int nf = 0; nf < 4; ++nf) {                                         \
      acc2[0][nf] = __builtin_amdgcn_mfma_f32_16x16x32_bf16(                 \
          a0, REGS[nf], acc2[0][nf], 0, 0, 0);                               \
      acc2[1][nf] = __builtin_amdgcn_mfma_f32_16x16x32_bf16(                 \
          a1, REGS[nf], acc2[1][nf], 0, 0, 0);                               \
    }                                                                        \
    if ((G) * 8 + (KS) + 2 < 32) P2B(REGS, (G) * 8 + (KS) + 2);              \
  }

  for (int g = 0; g < 4; ++g) {        // 64-proto chunks of this wave's 256
    f32x4 acc2[2][4];
#pragma unroll
    for (int mf = 0; mf < 2; ++mf)
#pragma unroll
      for (int nf = 0; nf < 4; ++nf) acc2[mf][nf] = (f32x4)0.0f;

    P2KS(0, g, brA);
    P2KS(1, g, brB);
    P2KS(2, g, brA);
    P2KS(3, g, brB);
    P2KS(4, g, brA);
    P2KS(5, g, brB);
    P2KS(6, g, brA);
    P2KS(7, g, brB);

    // ---- epilogue for this 64-proto chunk (256B/row contiguous) ----
    float ppv[4];
#pragma unroll
    for (int nf = 0; nf < 4; ++nf) ppv[nf] = ppb[g * 64 + nf * 16 + l15];
#pragma unroll
    for (int mf = 0; mf < 2; ++mf)
#pragma unroll
      for (int r = 0; r < 4; ++r) {
        const size_t rowoff = (size_t)(mf * 16 + lhi * 4 + r) * NPROTO;
#pragma unroll
        for (int nf = 0; nf < 4; ++nf) {
          float d2 = fmaxf(1.0f + ppv[nf] - 2.0f * acc2[mf][nf][r], 0.0f);
          outb[rowoff + g * 64 + nf * 16 + l15] = -sqrtf(d2);
        }
      }
  }
#undef P2KS
#undef P2B
}

extern "C" void kernel_launch(void* const* d_in, const int* in_sizes, int n_in,
                              void* d_out, int out_size, void* d_ws, size_t ws_size,
                              hipStream_t stream) {
  const float* X     = (const float*)d_in[0];  // [16384,1024]
  const float* mean  = (const float*)d_in[1];  // [1024]
  const float* proj  = (const float*)d_in[2];  // [1024,256]
  const float* proto = (const float*)d_in[3];  // [2048,256]
  float* out = (float*)d_out;                  // [16384,2048]

  char* ws = (char*)d_ws;
  // workspace layout (~1.5 MB total)
  size_t off = 0;
  unsigned short* projT_sw = (unsigned short*)(ws + off); off += (size_t)DIM * DP * 2;    // 512 KB
  unsigned short* Pb_sw    = (unsigned short*)(ws + off); off += (size_t)NPROTO * DP * 2; // 1 MB
  float* pp                = (float*)(ws + off);          off += (size_t)NPROTO * 4;      // 8 KB

  hipLaunchKernelGGL(k_prep, dim3(384 + NPROTO), dim3(256), 0, stream,
                     proj, proto, projT_sw, Pb_sw, pp);
  hipLaunchKernelGGL(k_fused, dim3(N_ROWS / 32), dim3(512), 0, stream,
                     X, mean, projT_sw, Pb_sw, pp, out);
}

// Round 19
// 60.126 us; speedup vs baseline: 1.6423x; 1.6423x over previous
//
#include <hip/hip_runtime.h>
#include <hip/hip_bf16.h>

// Problem shape (fixed by setup_inputs): B=8, Q=2048 -> N=16384 rows,
// D=1024, Dp=256, K=2048 prototypes.
#define N_ROWS 16384
#define DIM    1024
#define DP     256
#define NPROTO 2048

typedef float f32x4 __attribute__((ext_vector_type(4)));
typedef short s16x8 __attribute__((ext_vector_type(8)));
typedef short s16x4 __attribute__((ext_vector_type(4)));

__device__ __forceinline__ unsigned short f2bf(float f) {
  __hip_bfloat16 h = __float2bfloat16(f);   // RNE
  return __builtin_bit_cast(unsigned short, h);
}

// LDS-only barrier (no vmcnt drain; global prefetches stay in flight).
__device__ __forceinline__ void lds_barrier() {
  asm volatile("s_waitcnt lgkmcnt(0)" ::: "memory");
  __builtin_amdgcn_s_barrier();
}

// ---- prep: build FRAGMENT-ORDER operands ----
// projT_sw[cg][kb][lane][8]: cg in [0,16) 16-col groups of proj-output,
//   kb in [0,32) 32-wide K chunks; lane's 8 bf16 = proj[kb*32+(lane>>4)*8+j][cg*16+(lane&15)].
// Pb_sw[pgrp][kb][lane][8]: pgrp in [0,128) 16-proto groups, kb in [0,8);
//   lane's 8 bf16 = proto[pgrp*16+(lane&15)][kb*32+(lane>>4)*8+j].
// A wave's MFMA B-fragment load is then base + lane*16B: one coalesced 1KB read.
__global__ void k_prep(const float* __restrict__ proj,
                       const float* __restrict__ P,
                       unsigned short* __restrict__ projT_sw,
                       unsigned short* __restrict__ Pb_sw,
                       float* __restrict__ pp) {
  int b = blockIdx.x;
  int t = threadIdx.x;
  if (b < 128) {                      // projT_sw: 32768 16B chunks
    int q    = b * 256 + t;
    int lane = q & 63, kb = (q >> 6) & 31, cg = q >> 11;
    int c  = cg * 16 + (lane & 15);
    int k0 = kb * 32 + (lane >> 4) * 8;
    s16x8 v;
#pragma unroll
    for (int j = 0; j < 8; ++j)
      v[j] = (short)f2bf(proj[(size_t)(k0 + j) * DP + c]);
    *(s16x8*)(projT_sw + (size_t)q * 8) = v;
  } else if (b < 384) {               // Pb_sw: 65536 16B chunks
    int q    = (b - 128) * 256 + t;
    int lane = q & 63, kb = (q >> 6) & 7, pg = q >> 9;
    const float* src = P + (size_t)(pg * 16 + (lane & 15)) * DP +
                       kb * 32 + (lane >> 4) * 8;
    s16x8 v;
#pragma unroll
    for (int j = 0; j < 8; ++j) v[j] = (short)f2bf(src[j]);
    *(s16x8*)(Pb_sw + (size_t)q * 8) = v;
  } else {                            // pp: one block per proto
    int k = b - 384;
    float v = P[(size_t)k * DP + t];
    float s = v * v;
#pragma unroll
    for (int o = 1; o < 64; o <<= 1) s += __shfl_xor(s, o, 64);
    __shared__ float ws4[4];
    if ((t & 63) == 0) ws4[t >> 6] = s;
    __syncthreads();
    if (t == 0) pp[k] = ws4[0] + ws4[1] + ws4[2] + ws4[3];
  }
}

// ---- FUSED: 32 rows/block, 512 threads = 8 waves, grid 512 -> 2 blocks/CU ----
// Phase 1 (16 steps, BK=64, lds_barrier only): X staged via LDS
//   with 2-deep reg prefetch; B reg-direct coalesced from projT_sw.
// Handoff: row-norms, normalized Z -> Zs (3 lds_barriers).
// Phase 2 (ZERO barriers): each wave owns ALL 32 rows x protos wv*256..+256
//   (row-independent B reads -> minimal L2 traffic, 1 MB/block);
//   A-frags re-read per-ks from LDS-resident Zs (keeps VGPR <= 128 so two
//   blocks stay resident); B coalesced 2-deep from Pb_sw; -sqrt streamed.
__global__ __launch_bounds__(512, 4)
void k_fused(const float* __restrict__ X, const float* __restrict__ mean,
             const unsigned short* __restrict__ projT_sw,
             const unsigned short* __restrict__ Pb_sw,
             const float* __restrict__ pp, float* __restrict__ out) {
  __shared__ __align__(16) unsigned short Zs[32][264];   // 16896 B
  __shared__ __align__(16) unsigned short As[2][32][72]; //  9216 B
  __shared__ __align__(16) float mean_s[DIM];            //  4096 B
  __shared__ float rowsq[8][32];                         //  1024 B
  __shared__ float invs[32];                             //   128 B

  const int tid  = threadIdx.x;
  const int lane = tid & 63;
  const int wv   = tid >> 6;        // wave id 0..7
  const int l15  = lane & 15;
  const int lhi  = lane >> 4;
  const int rb   = blockIdx.x * 32;

  // stage mean once
  if (tid < 256)
    *(f32x4*)&mean_s[tid * 4] = *(const f32x4*)(mean + tid * 4);
  __syncthreads();

  // phase-1 staging coords: thread stages row tid>>4, cols (tid&15)*4 (+t*64)
  const int arow = tid >> 4;             // [0,32)
  const int ach  = (tid & 15) * 4;
  const float* xbase = X + (size_t)(rb + arow) * DIM + ach;
  // phase-1 B base: wave wv covers col-groups 2wv, 2wv+1
  const unsigned short* pj_base =
      projT_sw + (size_t)(wv * 2) * 32 * 64 * 8 + (size_t)lane * 8;

  f32x4 acc[2][2];
#pragma unroll
  for (int mf = 0; mf < 2; ++mf)
#pragma unroll
    for (int cg = 0; cg < 2; ++cg) acc[mf][cg] = (f32x4)0.0f;

  f32x4 xA, xB;
  s16x8 bfA[4], bfB[4];   // [cgi*2+kk]

#define P1X(XR, T) { XR = *(const f32x4*)(xbase + (T) * 64); }
#define P1B(REGS, T)                                                         \
  {                                                                          \
    _Pragma("unroll")                                                        \
    for (int cgi = 0; cgi < 2; ++cgi)                                        \
      _Pragma("unroll")                                                      \
      for (int kk = 0; kk < 2; ++kk)                                         \
        REGS[cgi * 2 + kk] = *(const s16x8*)(pj_base +                       \
            (size_t)(cgi * 32 + (T) * 2 + kk) * 512);                        \
  }
#define P1W(CUR, XR, T)                                                      \
  {                                                                          \
    f32x4 m0 = *(const f32x4*)&mean_s[(T) * 64 + ach];                       \
    f32x4 c0 = XR - m0;                                                      \
    s16x4 v;                                                                 \
    v[0] = (short)f2bf(c0[0]); v[1] = (short)f2bf(c0[1]);                    \
    v[2] = (short)f2bf(c0[2]); v[3] = (short)f2bf(c0[3]);                    \
    *(s16x4*)(&As[CUR][arow][ach]) = v;                                      \
  }
#define P1C(CUR, BF)                                                         \
  {                                                                          \
    s16x8 a[2][2];                                                           \
    _Pragma("unroll")                                                        \
    for (int mf = 0; mf < 2; ++mf)                                           \
      _Pragma("unroll")                                                      \
      for (int kk = 0; kk < 2; ++kk)                                         \
        a[mf][kk] = *(const s16x8*)(&As[CUR][mf * 16 + l15][kk * 32 + lhi * 8]); \
    _Pragma("unroll")                                                        \
    for (int mf = 0; mf < 2; ++mf)                                           \
      _Pragma("unroll")                                                      \
      for (int cgi = 0; cgi < 2; ++cgi)                                      \
        _Pragma("unroll")                                                    \
        for (int kk = 0; kk < 2; ++kk)                                       \
          acc[mf][cgi] = __builtin_amdgcn_mfma_f32_16x16x32_bf16(            \
              a[mf][kk], BF[cgi * 2 + kk], acc[mf][cgi], 0, 0, 0);           \
  }

  P1X(xA, 0); P1B(bfA, 0);
  P1X(xB, 1); P1B(bfB, 1);
  for (int t = 0; t < 16; t += 2) {
    P1W(0, xA, t);
    if (t + 2 < 16) P1X(xA, t + 2);
    lds_barrier();
    P1C(0, bfA);
    if (t + 2 < 16) P1B(bfA, t + 2);
    P1W(1, xB, t + 1);
    if (t + 3 < 16) P1X(xB, t + 3);
    lds_barrier();
    P1C(1, bfB);
    if (t + 3 < 16) P1B(bfB, t + 3);
  }
#undef P1X
#undef P1B
#undef P1W
#undef P1C

  // issue phase-2 first B loads now (survive the handoff barriers).
  // wave wv owns protos wv*256..+256 = proto-groups wv*16..+16.
  const unsigned short* pb_base =
      Pb_sw + (size_t)(wv * 16) * 8 * 64 * 8 + (size_t)lane * 8;
  s16x8 brA[4], brB[4];
#define P2B(REGS, T)                                                         \
  {                                                                          \
    const int g_ = (T) >> 3, k_ = (T) & 7;                                   \
    _Pragma("unroll")                                                        \
    for (int nf = 0; nf < 4; ++nf)                                           \
      REGS[nf] = *(const s16x8*)(pb_base +                                   \
          (size_t)((g_ * 4 + nf) * 8 + k_) * 512);                           \
  }
  P2B(brA, 0);
  P2B(brB, 1);

  // ---- handoff: row norms + normalized Z -> Zs ----
#pragma unroll
  for (int mf = 0; mf < 2; ++mf)
#pragma unroll
    for (int r = 0; r < 4; ++r) {
      float s = acc[mf][0][r] * acc[mf][0][r] + acc[mf][1][r] * acc[mf][1][r];
#pragma unroll
      for (int o = 1; o < 16; o <<= 1) s += __shfl_xor(s, o, 16);
      if (l15 == 0) rowsq[wv][mf * 16 + lhi * 4 + r] = s;
    }
  lds_barrier();
  if (tid < 32) {
    float n2 = 0.0f;
#pragma unroll
    for (int w = 0; w < 8; ++w) n2 += rowsq[w][tid];
    invs[tid] = 1.0f / fmaxf(sqrtf(n2), 1e-12f);  // F.normalize eps
  }
  lds_barrier();
#pragma unroll
  for (int mf = 0; mf < 2; ++mf)
#pragma unroll
    for (int r = 0; r < 4; ++r) {
      int row   = mf * 16 + lhi * 4 + r;
      float inv = invs[row];
#pragma unroll
      for (int cgi = 0; cgi < 2; ++cgi)
        Zs[row][wv * 32 + cgi * 16 + l15] = f2bf(acc[mf][cgi][r] * inv);
    }
  lds_barrier();

  // ================= phase 2 (no barriers) =================
  const float* ppb = pp + wv * 256;
  float* outb = out + (size_t)rb * NPROTO + wv * 256;

  for (int g = 0; g < 4; ++g) {        // 64-proto chunks of this wave's 256
    f32x4 acc2[2][4];
#pragma unroll
    for (int mf = 0; mf < 2; ++mf)
#pragma unroll
      for (int nf = 0; nf < 4; ++nf) acc2[mf][nf] = (f32x4)0.0f;

#pragma unroll
    for (int ks = 0; ks < 8; ks += 2) {
      const int t = g * 8 + ks;
      {
        s16x8 a0 = *(const s16x8*)(&Zs[l15][ks * 32 + lhi * 8]);
        s16x8 a1 = *(const s16x8*)(&Zs[16 + l15][ks * 32 + lhi * 8]);
#pragma unroll
        for (int nf = 0; nf < 4; ++nf) {
          acc2[0][nf] = __builtin_amdgcn_mfma_f32_16x16x32_bf16(
              a0, brA[nf], acc2[0][nf], 0, 0, 0);
          acc2[1][nf] = __builtin_amdgcn_mfma_f32_16x16x32_bf16(
              a1, brA[nf], acc2[1][nf], 0, 0, 0);
        }
      }
      if (t + 2 < 32) P2B(brA, t + 2);
      {
        s16x8 a0 = *(const s16x8*)(&Zs[l15][(ks + 1) * 32 + lhi * 8]);
        s16x8 a1 = *(const s16x8*)(&Zs[16 + l15][(ks + 1) * 32 + lhi * 8]);
#pragma unroll
        for (int nf = 0; nf < 4; ++nf) {
          acc2[0][nf] = __builtin_amdgcn_mfma_f32_16x16x32_bf16(
              a0, brB[nf], acc2[0][nf], 0, 0, 0);
          acc2[1][nf] = __builtin_amdgcn_mfma_f32_16x16x32_bf16(
              a1, brB[nf], acc2[1][nf], 0, 0, 0);
        }
      }
      if (t + 3 < 32) P2B(brB, t + 3);
    }

    // ---- epilogue for this 64-proto chunk ----
    float ppv[4];
#pragma unroll
    for (int nf = 0; nf < 4; ++nf) ppv[nf] = ppb[g * 64 + nf * 16 + l15];
#pragma unroll
    for (int mf = 0; mf < 2; ++mf)
#pragma unroll
      for (int r = 0; r < 4; ++r) {
        const size_t rowoff = (size_t)(mf * 16 + lhi * 4 + r) * NPROTO;
#pragma unroll
        for (int nf = 0; nf < 4; ++nf) {
          float d2 = fmaxf(1.0f + ppv[nf] - 2.0f * acc2[mf][nf][r], 0.0f);
          outb[rowoff + g * 64 + nf * 16 + l15] = -sqrtf(d2);
        }
      }
  }
#undef P2B
}

extern "C" void kernel_launch(void* const* d_in, const int* in_sizes, int n_in,
                              void* d_out, int out_size, void* d_ws, size_t ws_size,
                              hipStream_t stream) {
  const float* X     = (const float*)d_in[0];  // [16384,1024]
  const float* mean  = (const float*)d_in[1];  // [1024]
  const float* proj  = (const float*)d_in[2];  // [1024,256]
  const float* proto = (const float*)d_in[3];  // [2048,256]
  float* out = (float*)d_out;                  // [16384,2048]

  char* ws = (char*)d_ws;
  // workspace layout (~1.5 MB total)
  size_t off = 0;
  unsigned short* projT_sw = (unsigned short*)(ws + off); off += (size_t)DIM * DP * 2;    // 512 KB
  unsigned short* Pb_sw    = (unsigned short*)(ws + off); off += (size_t)NPROTO * DP * 2; // 1 MB
  float* pp                = (float*)(ws + off);          off += (size_t)NPROTO * 4;      // 8 KB

  hipLaunchKernelGGL(k_prep, dim3(384 + NPROTO), dim3(256), 0, stream,
                     proj, proto, projT_sw, Pb_sw, pp);
  hipLaunchKernelGGL(k_fused, dim3(N_ROWS / 32), dim3(512), 0, stream,
                     X, mean, projT_sw, Pb_sw, pp, out);
}